// Round 1
// baseline (13.724 us; speedup 1.0000x reference)
//
#include <hip/hip_runtime.h>

#define FH 128
#define FW 128
#define MIN_RADIUS 2

__global__ void __launch_bounds__(64)
stamp_gaussians(const float* __restrict__ boxes,
                const float* __restrict__ scores,
                float* __restrict__ out,
                int N) {
    const int box = blockIdx.x;          // flat b*N + n
    const int b   = box / N;

    // box layout: [x, y, z, w(dx), l(dy), h, yaw]
    const float* bx = boxes + (size_t)box * 7;
    const float x = bx[0];
    const float y = bx[1];
    const float w = bx[3];
    const float l = bx[4];

    const float scale = 0.8f;            // VOXEL * OUT_FACTOR
    const float w_fm = w / scale;
    const float l_fm = l / scale;

    bool valid = (w_fm > 0.0f) && (l_fm > 0.0f) &&
                 (w_fm <= 1000.0f) && (l_fm <= 1000.0f);

    // gaussian_radius(height=l_fm, width=w_fm, min_overlap=0.2), f32 math
    const float h  = l_fm;
    const float wd = w_fm;
    const float ov = 0.2f;

    const float b1  = h + wd;
    const float c1  = wd * h * (1.0f - ov) / (1.0f + ov);
    const float sq1 = sqrtf(fmaxf(b1 * b1 - 4.0f * c1, 0.0f));
    const float r1  = (b1 + sq1) * 0.5f;

    const float b2  = 2.0f * (h + wd);
    const float c2  = (1.0f - ov) * wd * h;
    const float sq2 = sqrtf(fmaxf(b2 * b2 - 16.0f * c2, 0.0f));
    const float r2  = (b2 + sq2) * 0.5f;

    const float a3  = 4.0f * ov;
    const float b3  = -2.0f * ov * (h + wd);
    const float c3  = (ov - 1.0f) * wd * h;
    const float sq3 = sqrtf(fmaxf(b3 * b3 - 4.0f * a3 * c3, 0.0f));
    const float r3  = (b3 + sq3) * 0.5f;

    float r = fminf(fminf(r1, r2), r3);
    if (!valid) r = (float)MIN_RADIUS;
    const int radius = max(MIN_RADIUS, (int)floorf(r));

    // center, truncation toward zero matches astype(int32)
    const int cx = (int)((x - (-51.2f)) / scale);
    const int cy = (int)((y - (-51.2f)) / scale);
    valid = valid && (cx >= 0) && (cx < FW) && (cy >= 0) && (cy < FH);
    if (!valid) return;

    const float sigma   = (2.0f * (float)radius + 1.0f) / 6.0f;
    const float denom   = 2.0f * sigma * sigma;
    const float score   = scores[box];
    const float eps     = 1.1920928955078125e-07f;   // finfo(f32).eps = 2^-23

    const int W    = 2 * radius + 1;
    const int npix = W * W;
    float* outb = out + (size_t)b * FH * FW;

    for (int p = threadIdx.x; p < npix; p += blockDim.x) {
        const int oy = p / W - radius;
        const int ox = p % W - radius;
        const int gy = cy + oy;
        const int gx = cx + ox;
        if (gy < 0 || gy >= FH || gx < 0 || gx >= FW) continue;

        const float d2 = (float)(oy * oy + ox * ox);
        float g = expf(-d2 / denom);
        if (g < eps) g = 0.0f;
        const float val = g * score;
        if (val > 0.0f) {
            // all stamped values are >= 0: uint bit-pattern max == float max
            atomicMax((unsigned int*)&outb[gy * FW + gx], __float_as_uint(val));
        }
    }
}

extern "C" void kernel_launch(void* const* d_in, const int* in_sizes, int n_in,
                              void* d_out, int out_size, void* d_ws, size_t ws_size,
                              hipStream_t stream) {
    const float* boxes  = (const float*)d_in[0];
    const float* scores = (const float*)d_in[1];
    float* out = (float*)d_out;

    // out is (B,1,128,128); derive B and N from sizes (batch_size lives on device)
    const int B = out_size / (FH * FW);
    const int N = in_sizes[1] / B;

    // d_out is poisoned (0xAA...) before timing and not re-poisoned between
    // replays -> must zero every call. Memset node is graph-capture legal.
    hipMemsetAsync(d_out, 0, (size_t)out_size * sizeof(float), stream);

    stamp_gaussians<<<B * N, 64, 0, stream>>>(boxes, scores, out, N);
}